// Round 7
// baseline (163.221 us; speedup 1.0000x reference)
//
#include <hip/hip_runtime.h>

#define BB 64
#define NN 512
#define FD 64

typedef short bf16x8 __attribute__((ext_vector_type(8)));
typedef float f32x4 __attribute__((ext_vector_type(4)));

__device__ __forceinline__ unsigned short f2bf(float f){
    unsigned u = __builtin_bit_cast(unsigned, f);
    u += 0x7fffu + ((u >> 16) & 1u);           // RNE
    return (unsigned short)(u >> 16);
}
__device__ __forceinline__ float bf2f(unsigned short h){
    unsigned u = ((unsigned)h) << 16;
    return __builtin_bit_cast(float, u);
}
__device__ __forceinline__ float fast_tanh(float x){
    float e = __expf(2.0f * x);                 // inf -> 1, 0 -> -1: saturates correctly
    return 1.0f - 2.0f * __builtin_amdgcn_rcpf(e + 1.0f);
}
// Workgroup barrier that orders LDS only: waits lgkmcnt(0), leaves vmcnt
// untouched so prefetched global loads stay in flight across the barrier
// (HIP __syncthreads drains vmcnt(0) — the documented ~20%+ stall).
// gfx9 s_waitcnt imm: vm[3:0]=0xF, exp[6:4]=7, lgkm[11:8]=0, vm[15:14]=3 -> 0xC07F
__device__ __forceinline__ void bar_lds(){
    asm volatile("" ::: "memory");
    __builtin_amdgcn_s_waitcnt(0xC07F);
    __builtin_amdgcn_s_barrier();
    asm volatile("" ::: "memory");
}

// XW = X @ W via MFMA (W transposed in-block);
// emits XWh[b][n][f] (natural) and XWt[b][f][n] (transposed), bf16
__global__ __launch_bounds__(256) void k_xw(const float* __restrict__ X,
                                            const float* __restrict__ W,
                                            unsigned short* __restrict__ XWh,
                                            unsigned short* __restrict__ XWt){
    __shared__ unsigned short Xl[64][72];
    __shared__ unsigned short Wtl[64][72];
    __shared__ unsigned short Cl[64][72];    // C natural [n][f]
    __shared__ unsigned short ClT[64][72];   // C transposed [f][n]
    int t = threadIdx.x;
    int row0 = blockIdx.x * 64;
    int r = t >> 2, c0 = (t & 3) * 16;
    {   // W rows r (c-index) -> scatter transpose to Wtl[d][c]
        const float4* wsrc = (const float4*)&W[r*64 + c0];
        #pragma unroll
        for (int q = 0; q < 4; q++){
            float4 v = wsrc[q];
            Wtl[c0 + q*4 + 0][r] = f2bf(v.x);
            Wtl[c0 + q*4 + 1][r] = f2bf(v.y);
            Wtl[c0 + q*4 + 2][r] = f2bf(v.z);
            Wtl[c0 + q*4 + 3][r] = f2bf(v.w);
        }
        const float4* src = (const float4*)&X[(row0 + r)*FD + c0];
        #pragma unroll
        for (int q = 0; q < 4; q++){
            float4 v = src[q];
            ushort4 h; h.x=f2bf(v.x); h.y=f2bf(v.y); h.z=f2bf(v.z); h.w=f2bf(v.w);
            *(ushort4*)&Xl[r][c0 + q*4] = h;
        }
    }
    __syncthreads();
    int lane = t & 63, w = t >> 6, l15 = lane & 15, quad = lane >> 4;
    f32x4 acc[4] = {{0,0,0,0},{0,0,0,0},{0,0,0,0},{0,0,0,0}};
    #pragma unroll
    for (int ks = 0; ks < 2; ks++){
        bf16x8 af = *(const bf16x8*)&Xl[w*16 + l15][ks*32 + quad*8];
        #pragma unroll
        for (int nt = 0; nt < 4; nt++){
            bf16x8 bfr = *(const bf16x8*)&Wtl[nt*16 + l15][ks*32 + quad*8];
            acc[nt] = __builtin_amdgcn_mfma_f32_16x16x32_bf16(af, bfr, acc[nt], 0, 0, 0);
        }
    }
    #pragma unroll
    for (int nt = 0; nt < 4; nt++)
        #pragma unroll
        for (int rg = 0; rg < 4; rg++){
            unsigned short hb = f2bf(acc[nt][rg]);
            Cl [w*16 + quad*4 + rg][nt*16 + l15] = hb;
            ClT[nt*16 + l15][w*16 + quad*4 + rg] = hb;
        }
    __syncthreads();
    int b = blockIdx.x >> 3, n0 = (blockIdx.x & 7) * 64;
    {
        uint4 v0 = *(const uint4*)&Cl[r][c0];
        uint4 v1 = *(const uint4*)&Cl[r][c0 + 8];
        *(uint4*)&XWh[(row0 + r)*FD + c0]     = v0;
        *(uint4*)&XWh[(row0 + r)*FD + c0 + 8] = v1;
    }
    {
        uint4 v0 = *(const uint4*)&ClT[r][c0];
        uint4 v1 = *(const uint4*)&ClT[r][c0 + 8];
        *(uint4*)&XWt[(b*64 + r)*NN + n0 + c0]     = v0;
        *(uint4*)&XWt[(b*64 + r)*NN + n0 + c0 + 8] = v1;
    }
}

// Fused per 64-row i-tile: M = (A_ @ XW) * diag(colsum) (LDS round-trip), then
// H = tanh(M @ XW^T + rowsum*bias_a) @ XW + bias_W  (flash over 8 j-chunks).
// B-operand fragments come DIRECTLY from global (L2-hot, 16B/lane contiguous);
// LDS holds only the A-chunk dbuf (phase A) / P dbuf (phase B): 2 slots.
// All barriers are lgkm-only (bar_lds) so global prefetches survive them.
// 512 thr / 8 waves: wave w -> rows (w&3)*16, cols (w>>2)*32 (2 col-tiles)
__global__ __launch_bounds__(512, 6) void k_fused(const float* __restrict__ A,
                                                  const unsigned short* __restrict__ XWh,
                                                  const unsigned short* __restrict__ XWt,
                                                  const float* __restrict__ a,
                                                  const int* __restrict__ Ni,
                                                  const float* __restrict__ bias_a,
                                                  const float* __restrict__ bias_W,
                                                  float* __restrict__ H){
    __shared__ unsigned short buf[2][64][72];   // phase A: A-chunk dbuf; phase B: M then P dbuf
    __shared__ float cspart[8][64];
    __shared__ float csl[64];
    __shared__ float rspart[64][8];
    __shared__ float rsl[64];
    __shared__ float bl[512];
    int t = threadIdx.x;
    int b = blockIdx.x, it = blockIdx.y;       // batch on x: a batch's 8 blocks share an XCD L2
    int i0 = it * 64;
    int Nb = (Ni[1] == 0) ? Ni[2*b] : Ni[b];   // int64 vs int32 layout
    int lane = t & 63, w = t >> 6, l15 = lane & 15, quad = lane >> 4;
    int wr = w & 3, wc = w >> 2;
    int r8 = t >> 3, c4 = (t & 7) * 4;
    const float* Ab = A + (b*NN + i0)*NN;
    const unsigned short* XWtb = XWt + b*64*NN;
    const unsigned short* XWhb = XWh + b*NN*FD;

    {   // colsum partials from a (tiny, L2-hot; reduced later)
        int cd = t & 63, cp = t >> 6;
        float s = 0.f;
        #pragma unroll
        for (int i = 0; i < 8; i++) s += a[(cp*8 + i)*64 + cd];
        cspart[cp][cd] = s;
    }
    bl[t] = bias_a[t];

    // ---- phase A: M = A_ @ XW over 8 k-chunks ----
    // A: depth-2 register prefetch (HBM); B-frags: depth-1 from global (L2-hot)
    float4 pA[2][2];
    pA[0][0] = *(const float4*)&Ab[r8*NN + c4];
    pA[0][1] = *(const float4*)&Ab[r8*NN + 32 + c4];
    pA[1][0] = *(const float4*)&Ab[r8*NN + 64 + c4];
    pA[1][1] = *(const float4*)&Ab[r8*NN + 64 + 32 + c4];
    bf16x8 nB[2][2];
    #pragma unroll
    for (int ks = 0; ks < 2; ks++)
        #pragma unroll
        for (int nt = 0; nt < 2; nt++)
            nB[ks][nt] = *(const bf16x8*)&XWtb[(wc*32 + nt*16 + l15)*NN + ks*32 + quad*8];
    f32x4 acc[2] = {{0,0,0,0},{0,0,0,0}};
    float rs = 0.f;
    #pragma unroll
    for (int c = 0; c < 8; c++){
        {   // stage chunk c (fp32 -> bf16, rowsum on the fly)
            float4 v = pA[c & 1][0];
            rs += v.x + v.y + v.z + v.w;
            ushort4 h; h.x=f2bf(v.x); h.y=f2bf(v.y); h.z=f2bf(v.z); h.w=f2bf(v.w);
            *(ushort4*)&buf[c & 1][r8][c4] = h;
            v = pA[c & 1][1];
            rs += v.x + v.y + v.z + v.w;
            ushort4 h2; h2.x=f2bf(v.x); h2.y=f2bf(v.y); h2.z=f2bf(v.z); h2.w=f2bf(v.w);
            *(ushort4*)&buf[c & 1][r8][32 + c4] = h2;
        }
        bar_lds();                           // lgkm-only: prefetches stay in flight
        if (c < 6){                          // depth-2 A prefetch
            pA[c & 1][0] = *(const float4*)&Ab[r8*NN + (c+2)*64 + c4];
            pA[c & 1][1] = *(const float4*)&Ab[r8*NN + (c+2)*64 + 32 + c4];
        }
        bf16x8 uB[2][2];
        #pragma unroll
        for (int ks = 0; ks < 2; ks++)
            #pragma unroll
            for (int nt = 0; nt < 2; nt++)
                uB[ks][nt] = nB[ks][nt];
        if (c < 7){                          // depth-1 B-frag prefetch (L2)
            #pragma unroll
            for (int ks = 0; ks < 2; ks++)
                #pragma unroll
                for (int nt = 0; nt < 2; nt++)
                    nB[ks][nt] = *(const bf16x8*)&XWtb[(wc*32 + nt*16 + l15)*NN + (c+1)*64 + ks*32 + quad*8];
        }
        #pragma unroll
        for (int ks = 0; ks < 2; ks++){
            bf16x8 af = *(const bf16x8*)&buf[c & 1][wr*16 + l15][ks*32 + quad*8];
            #pragma unroll
            for (int nt = 0; nt < 2; nt++)
                acc[nt] = __builtin_amdgcn_mfma_f32_16x16x32_bf16(af, uB[ks][nt], acc[nt], 0, 0, 0);
        }
    }
    // diagonal of A_: M[i,:] += XW[i,:] for i < Nb (L2-hot scalar reads)
    #pragma unroll
    for (int nt = 0; nt < 2; nt++)
        #pragma unroll
        for (int rg = 0; rg < 4; rg++){
            int iloc = wr*16 + quad*4 + rg;
            if (i0 + iloc < Nb)
                acc[nt][rg] += bf2f(XWtb[(wc*32 + nt*16 + l15)*NN + i0 + iloc]);
        }
    rspart[r8][t & 7] = rs;
    bar_lds();
    if (t < 64){
        float s = 0.f;
        #pragma unroll
        for (int p = 0; p < 8; p++) s += cspart[p][t];
        csl[t] = s;
    } else if (t < 128){
        int row = t - 64;
        float s = 0.f;
        #pragma unroll
        for (int p = 0; p < 8; p++) s += rspart[row][p];
        if (i0 + row < Nb) s += 1.f;
        rsl[row] = s;
    }
    bar_lds();
    // M = acc * colsum[col] -> buf[0] (layout transform C->A operand)
    #pragma unroll
    for (int nt = 0; nt < 2; nt++){
        float cs = csl[wc*32 + nt*16 + l15];
        #pragma unroll
        for (int rg = 0; rg < 4; rg++)
            buf[0][wr*16 + quad*4 + rg][wc*32 + nt*16 + l15] = f2bf(acc[nt][rg] * cs);
    }
    bar_lds();
    bf16x8 maf[2];
    maf[0] = *(const bf16x8*)&buf[0][wr*16 + l15][quad*8];
    maf[1] = *(const bf16x8*)&buf[0][wr*16 + l15][32 + quad*8];
    float rs_r[4];
    #pragma unroll
    for (int rg = 0; rg < 4; rg++) rs_r[rg] = rsl[wr*16 + quad*4 + rg];

    // ---- phase B: flash over 8 j-chunks; 1 lgkm barrier per chunk ----
    // P dbuf parity: jt=0 -> slot 1 (slot 0 still holds M until first barrier)
    bf16x8 g1[2][2], g2[2][2];
    #pragma unroll
    for (int ks = 0; ks < 2; ks++)
        #pragma unroll
        for (int nt = 0; nt < 2; nt++){
            g1[ks][nt] = *(const bf16x8*)&XWhb[(wc*32 + nt*16 + l15)*FD + ks*32 + quad*8];
            g2[ks][nt] = *(const bf16x8*)&XWtb[(wc*32 + nt*16 + l15)*NN + ks*32 + quad*8];
        }
    f32x4 hacc[2] = {{0,0,0,0},{0,0,0,0}};
    #pragma unroll
    for (int jt = 0; jt < 8; jt++){
        int ps = (jt & 1) ^ 1;
        // GEMM1: arg = M @ XW^T + rs*bias_a (B-frags from regs/global)
        f32x4 arg[2];
        #pragma unroll
        for (int nt = 0; nt < 2; nt++){
            float bv = bl[jt*64 + wc*32 + nt*16 + l15];
            arg[nt][0] = rs_r[0]*bv; arg[nt][1] = rs_r[1]*bv;
            arg[nt][2] = rs_r[2]*bv; arg[nt][3] = rs_r[3]*bv;
        }
        #pragma unroll
        for (int ks = 0; ks < 2; ks++)
            #pragma unroll
            for (int nt = 0; nt < 2; nt++)
                arg[nt] = __builtin_amdgcn_mfma_f32_16x16x32_bf16(maf[ks], g1[ks][nt], arg[nt], 0, 0, 0);
        if (jt < 7){   // prefetch next GEMM1 B-frags (covered by tanh + GEMM2)
            #pragma unroll
            for (int ks = 0; ks < 2; ks++)
                #pragma unroll
                for (int nt = 0; nt < 2; nt++)
                    g1[ks][nt] = *(const bf16x8*)&XWhb[((jt+1)*64 + wc*32 + nt*16 + l15)*FD + ks*32 + quad*8];
        }
        // P = tanh(arg) -> LDS slot ps (C->A layout transform)
        #pragma unroll
        for (int nt = 0; nt < 2; nt++)
            #pragma unroll
            for (int rg = 0; rg < 4; rg++)
                buf[ps][wr*16 + quad*4 + rg][wc*32 + nt*16 + l15] = f2bf(fast_tanh(arg[nt][rg]));
        bar_lds();
        // GEMM2: hacc += P @ XW
        #pragma unroll
        for (int ks = 0; ks < 2; ks++){
            bf16x8 paf = *(const bf16x8*)&buf[ps][wr*16 + l15][ks*32 + quad*8];
            #pragma unroll
            for (int dt = 0; dt < 2; dt++)
                hacc[dt] = __builtin_amdgcn_mfma_f32_16x16x32_bf16(paf, g2[ks][dt], hacc[dt], 0, 0, 0);
        }
        if (jt < 7){   // prefetch next GEMM2 B-frags (covered by next GEMM1)
            #pragma unroll
            for (int ks = 0; ks < 2; ks++)
                #pragma unroll
                for (int dt = 0; dt < 2; dt++)
                    g2[ks][dt] = *(const bf16x8*)&XWtb[(wc*32 + dt*16 + l15)*NN + (jt+1)*64 + ks*32 + quad*8];
        }
    }
    #pragma unroll
    for (int dt = 0; dt < 2; dt++){
        float bw = bias_W[wc*32 + dt*16 + l15];
        #pragma unroll
        for (int rg = 0; rg < 4; rg++)
            H[(b*NN + i0 + wr*16 + quad*4 + rg)*FD + wc*32 + dt*16 + l15] = hacc[dt][rg] + bw;
    }
}

extern "C" void kernel_launch(void* const* d_in, const int* in_sizes, int n_in,
                              void* d_out, int out_size, void* d_ws, size_t ws_size,
                              hipStream_t stream){
    const float* X      = (const float*)d_in[0];
    const float* A      = (const float*)d_in[1];
    const int*   N      = (const int*)  d_in[2];
    const float* W      = (const float*)d_in[3];
    const float* a      = (const float*)d_in[4];
    const float* bias_W = (const float*)d_in[5];
    const float* bias_a = (const float*)d_in[6];
    float* H = (float*)d_out;
    char* ws = (char*)d_ws;

    unsigned short* XWh = (unsigned short*)(ws);              // 4 MB
    unsigned short* XWt = (unsigned short*)(ws + (4u<<20));   // 4 MB

    k_xw   <<<BB * NN / 64, 256, 0, stream>>>(X, W, XWh, XWt);
    k_fused<<<dim3(BB, 8), 512, 0, stream>>>(A, XWh, XWt, a, N, bias_a, bias_W, H);
}

// Round 8
// 137.284 us; speedup vs baseline: 1.1889x; 1.1889x over previous
//
#include <hip/hip_runtime.h>

#define BB 64
#define NN 512
#define FD 64

typedef short bf16x8 __attribute__((ext_vector_type(8)));
typedef float f32x4 __attribute__((ext_vector_type(4)));

union bfpack { ushort u[8]; bf16x8 v; };

__device__ __forceinline__ unsigned short f2bf(float f){
    unsigned u = __builtin_bit_cast(unsigned, f);
    u += 0x7fffu + ((u >> 16) & 1u);           // RNE
    return (unsigned short)(u >> 16);
}
__device__ __forceinline__ float bf2f(unsigned short h){
    unsigned u = ((unsigned)h) << 16;
    return __builtin_bit_cast(float, u);
}
__device__ __forceinline__ float fast_tanh(float x){
    float e = __expf(2.0f * x);                 // inf -> 1, 0 -> -1: saturates correctly
    return 1.0f - 2.0f * __builtin_amdgcn_rcpf(e + 1.0f);
}
// lgkm-only workgroup barrier: leaves vmcnt untouched so global prefetches
// survive (HIP __syncthreads drains vmcnt(0)). imm 0xC07F = lgkm(0), vm/exp max.
__device__ __forceinline__ void bar_lds(){
    asm volatile("" ::: "memory");
    __builtin_amdgcn_s_waitcnt(0xC07F);
    __builtin_amdgcn_s_barrier();
    asm volatile("" ::: "memory");
}

// XW = X @ W via MFMA. Outputs in MFMA B-fragment-linear layout:
//   XWtf[b][c][g][ks][lane*8+j] = XW[n = c*64+ks*32+(lane>>4)*8+j][f = g*16+(lane&15)]
//   XWhf[b][c][g][ks][lane*8+j] = XW[n = c*64+g*16+(lane&15)][f = ks*32+(lane>>4)*8+j]
// so a wave's b-frag load is one contiguous 1KB segment (16B/lane coalesced).
__global__ __launch_bounds__(256) void k_xw(const float* __restrict__ X,
                                            const float* __restrict__ W,
                                            unsigned short* __restrict__ XWhf,
                                            unsigned short* __restrict__ XWtf){
    __shared__ unsigned short Xl[64][72];
    __shared__ unsigned short Wtl[64][72];
    __shared__ unsigned short Cl[64][72];    // C natural [n][f]
    __shared__ unsigned short ClT[64][72];   // C transposed [f][n]
    int t = threadIdx.x;
    int row0 = blockIdx.x * 64;
    int r = t >> 2, c0 = (t & 3) * 16;
    {   // W rows r (c-index) -> scatter transpose to Wtl[d][c]
        const float4* wsrc = (const float4*)&W[r*64 + c0];
        #pragma unroll
        for (int q = 0; q < 4; q++){
            float4 v = wsrc[q];
            Wtl[c0 + q*4 + 0][r] = f2bf(v.x);
            Wtl[c0 + q*4 + 1][r] = f2bf(v.y);
            Wtl[c0 + q*4 + 2][r] = f2bf(v.z);
            Wtl[c0 + q*4 + 3][r] = f2bf(v.w);
        }
        const float4* src = (const float4*)&X[(row0 + r)*FD + c0];
        #pragma unroll
        for (int q = 0; q < 4; q++){
            float4 v = src[q];
            ushort4 h; h.x=f2bf(v.x); h.y=f2bf(v.y); h.z=f2bf(v.z); h.w=f2bf(v.w);
            *(ushort4*)&Xl[r][c0 + q*4] = h;
        }
    }
    __syncthreads();
    int lane = t & 63, w = t >> 6, l15 = lane & 15, quad = lane >> 4;
    f32x4 acc[4] = {{0,0,0,0},{0,0,0,0},{0,0,0,0},{0,0,0,0}};
    #pragma unroll
    for (int ks = 0; ks < 2; ks++){
        bf16x8 af = *(const bf16x8*)&Xl[w*16 + l15][ks*32 + quad*8];
        #pragma unroll
        for (int nt = 0; nt < 4; nt++){
            bf16x8 bfr = *(const bf16x8*)&Wtl[nt*16 + l15][ks*32 + quad*8];
            acc[nt] = __builtin_amdgcn_mfma_f32_16x16x32_bf16(af, bfr, acc[nt], 0, 0, 0);
        }
    }
    #pragma unroll
    for (int nt = 0; nt < 4; nt++)
        #pragma unroll
        for (int rg = 0; rg < 4; rg++){
            unsigned short hb = f2bf(acc[nt][rg]);
            Cl [w*16 + quad*4 + rg][nt*16 + l15] = hb;
            ClT[nt*16 + l15][w*16 + quad*4 + rg] = hb;
        }
    __syncthreads();
    int b = blockIdx.x >> 3, cblk = blockIdx.x & 7;
    #pragma unroll
    for (int q = 0; q < 2; q++){
        int t2 = t + 256*q;            // 0..511 -> (g, ks, lane6)
        int g = t2 >> 7, ks = (t2 >> 6) & 1, lane6 = t2 & 63;
        int qd = lane6 >> 4, lb = lane6 & 15;
        uint4 vh = *(const uint4*)&Cl [g*16 + lb][ks*32 + qd*8];
        uint4 vt = *(const uint4*)&ClT[g*16 + lb][ks*32 + qd*8];
        long base = ((((long)b*8 + cblk)*4 + g)*2 + ks)*512 + lane6*8;
        *(uint4*)&XWhf[base] = vh;
        *(uint4*)&XWtf[base] = vt;
    }
}

// Fused per 64-row i-tile: phase A (NO barriers, no LDS operands):
//   M = (A_ @ XW) * diag(colsum); A-frags direct from global (128B segments),
//   B-frags direct from fragment-linear XWtf (1KB contiguous per wave-load).
// Phase B: H = tanh(M @ XW^T + rowsum*bias_a) @ XW + bias_W, flash over 8
//   j-chunks; LDS only for the M/P C->A layout transform (lgkm-only barriers).
// 512 thr / 8 waves: wave w -> rows (w&3)*16, cols (w>>2)*32 (2 col-tiles)
__global__ __launch_bounds__(512, 4) void k_fused(const float* __restrict__ A,
                                                  const unsigned short* __restrict__ XWhf,
                                                  const unsigned short* __restrict__ XWtf,
                                                  const float* __restrict__ a,
                                                  const int* __restrict__ Ni,
                                                  const float* __restrict__ bias_a,
                                                  const float* __restrict__ bias_W,
                                                  float* __restrict__ H){
    __shared__ unsigned short buf[2][64][72];   // M (slot0) / P dbuf
    __shared__ float cspart[8][64];
    __shared__ float bl[512];
    int t = threadIdx.x;
    int b = blockIdx.x, it = blockIdx.y;       // batch on x: 8 blocks of a batch share an XCD L2
    int i0 = it * 64;
    int Nb = (Ni[1] == 0) ? Ni[2*b] : Ni[b];   // int64 vs int32 layout
    int lane = t & 63, w = t >> 6, l15 = lane & 15, quad = lane >> 4;
    int wr = w & 3, wc = w >> 2;
    const unsigned short* XWtb = XWtf + (long)b*8*4*2*512;
    const unsigned short* XWhb = XWhf + (long)b*8*4*2*512;

    {   // colsum partials from a (read at M-boundary after bar_lds)
        int cd = t & 63, cp = t >> 6;
        float s = 0.f;
        #pragma unroll
        for (int i = 0; i < 8; i++) s += a[(cp*8 + i)*64 + cd];
        cspart[cp][cd] = s;
    }
    bl[t] = bias_a[t];

    // ---- phase A: barrier-free. A-frag rows owned per lane. ----
    const float* Arow = A + ((long)b*NN + i0 + wr*16 + l15)*NN;
    float4 pA[2][2][2];                         // [depth][ks][half]
    #pragma unroll
    for (int d = 0; d < 2; d++)
        #pragma unroll
        for (int ks = 0; ks < 2; ks++){
            pA[d][ks][0] = *(const float4*)&Arow[d*64 + ks*32 + quad*8];
            pA[d][ks][1] = *(const float4*)&Arow[d*64 + ks*32 + quad*8 + 4];
        }
    bf16x8 pB[2][2][2];                         // [depth][ks][nt]
    #pragma unroll
    for (int d = 0; d < 2; d++)
        #pragma unroll
        for (int ks = 0; ks < 2; ks++)
            #pragma unroll
            for (int nt = 0; nt < 2; nt++)
                pB[d][ks][nt] = *(const bf16x8*)&XWtb[(((long)d*4 + wc*2+nt)*2 + ks)*512 + lane*8];
    f32x4 acc[2] = {{0,0,0,0},{0,0,0,0}};
    float rsp = 0.f;
    #pragma unroll
    for (int c = 0; c < 8; c++){
        int par = c & 1;
        bf16x8 af[2];
        #pragma unroll
        for (int ks = 0; ks < 2; ks++){
            float4 v0 = pA[par][ks][0], v1 = pA[par][ks][1];
            rsp += v0.x+v0.y+v0.z+v0.w + v1.x+v1.y+v1.z+v1.w;
            bfpack p;
            p.u[0]=f2bf(v0.x); p.u[1]=f2bf(v0.y); p.u[2]=f2bf(v0.z); p.u[3]=f2bf(v0.w);
            p.u[4]=f2bf(v1.x); p.u[5]=f2bf(v1.y); p.u[6]=f2bf(v1.z); p.u[7]=f2bf(v1.w);
            af[ks] = p.v;
        }
        bf16x8 bb[2][2];
        #pragma unroll
        for (int ks = 0; ks < 2; ks++)
            #pragma unroll
            for (int nt = 0; nt < 2; nt++)
                bb[ks][nt] = pB[par][ks][nt];
        if (c < 6){   // depth-2 refill
            #pragma unroll
            for (int ks = 0; ks < 2; ks++){
                pA[par][ks][0] = *(const float4*)&Arow[(c+2)*64 + ks*32 + quad*8];
                pA[par][ks][1] = *(const float4*)&Arow[(c+2)*64 + ks*32 + quad*8 + 4];
                #pragma unroll
                for (int nt = 0; nt < 2; nt++)
                    pB[par][ks][nt] = *(const bf16x8*)&XWtb[((((long)c+2)*4 + wc*2+nt)*2 + ks)*512 + lane*8];
            }
        }
        #pragma unroll
        for (int ks = 0; ks < 2; ks++)
            #pragma unroll
            for (int nt = 0; nt < 2; nt++)
                acc[nt] = __builtin_amdgcn_mfma_f32_16x16x32_bf16(af[ks], bb[ks][nt], acc[nt], 0, 0, 0);
    }
    // rowsum: lanes {l15, ^16, ^32} hold quad-slices of row wr*16+l15
    rsp += __shfl_xor(rsp, 16, 64);
    rsp += __shfl_xor(rsp, 32, 64);
    float rs_r[4];
    #pragma unroll
    for (int rg = 0; rg < 4; rg++){
        rs_r[rg] = __shfl(rsp, quad*4 + rg, 64);
        if (i0 + wr*16 + quad*4 + rg < Nb) rs_r[rg] += 1.f;
    }
    // diagonal of A_: acc[i-local][f] += XW[i][f] for i < Nb (L2-hot scalar reads from XWtf)
    #pragma unroll
    for (int nt = 0; nt < 2; nt++)
        #pragma unroll
        for (int rg = 0; rg < 4; rg++){
            int iloc = wr*16 + quad*4 + rg;
            if (i0 + iloc < Nb){
                int ksd = iloc >> 5, qdd = (iloc >> 3) & 3, jd = iloc & 7;
                acc[nt][rg] += bf2f(XWtb[(((long)it*4 + wc*2+nt)*2 + ksd)*512 + (qdd*16 + l15)*8 + jd]);
            }
        }
    bar_lds();   // cspart/bl visible; buf free
    float cs[2];
    #pragma unroll
    for (int nt = 0; nt < 2; nt++){
        float s = 0.f;
        #pragma unroll
        for (int p = 0; p < 8; p++) s += cspart[p][wc*32 + nt*16 + l15];
        cs[nt] = s;
    }
    // M = acc * colsum[col] -> buf[0] (C->A operand layout transform)
    #pragma unroll
    for (int nt = 0; nt < 2; nt++)
        #pragma unroll
        for (int rg = 0; rg < 4; rg++)
            buf[0][wr*16 + quad*4 + rg][wc*32 + nt*16 + l15] = f2bf(acc[nt][rg] * cs[nt]);
    bar_lds();
    bf16x8 maf[2];
    maf[0] = *(const bf16x8*)&buf[0][wr*16 + l15][quad*8];
    maf[1] = *(const bf16x8*)&buf[0][wr*16 + l15][32 + quad*8];

    // ---- phase B: flash over 8 j-chunks; 1 lgkm barrier per chunk ----
    bf16x8 pG1[2][2], pG2[2][2];
    #pragma unroll
    for (int ks = 0; ks < 2; ks++)
        #pragma unroll
        for (int nt = 0; nt < 2; nt++){
            pG1[ks][nt] = *(const bf16x8*)&XWhb[(((long)0*4 + wc*2+nt)*2 + ks)*512 + lane*8];
            pG2[ks][nt] = *(const bf16x8*)&XWtb[(((long)0*4 + wc*2+nt)*2 + ks)*512 + lane*8];
        }
    f32x4 hacc[2] = {{0,0,0,0},{0,0,0,0}};
    #pragma unroll
    for (int jt = 0; jt < 8; jt++){
        int ps = (jt & 1) ^ 1;      // jt=0 -> slot1 (slot0 holds M until first barrier)
        f32x4 arg[2];
        #pragma unroll
        for (int nt = 0; nt < 2; nt++){
            float bv = bl[jt*64 + wc*32 + nt*16 + l15];
            arg[nt][0] = rs_r[0]*bv; arg[nt][1] = rs_r[1]*bv;
            arg[nt][2] = rs_r[2]*bv; arg[nt][3] = rs_r[3]*bv;
        }
        #pragma unroll
        for (int ks = 0; ks < 2; ks++)
            #pragma unroll
            for (int nt = 0; nt < 2; nt++)
                arg[nt] = __builtin_amdgcn_mfma_f32_16x16x32_bf16(maf[ks], pG1[ks][nt], arg[nt], 0, 0, 0);
        if (jt < 7){
            #pragma unroll
            for (int ks = 0; ks < 2; ks++)
                #pragma unroll
                for (int nt = 0; nt < 2; nt++)
                    pG1[ks][nt] = *(const bf16x8*)&XWhb[((((long)jt+1)*4 + wc*2+nt)*2 + ks)*512 + lane*8];
        }
        #pragma unroll
        for (int nt = 0; nt < 2; nt++)
            #pragma unroll
            for (int rg = 0; rg < 4; rg++)
                buf[ps][wr*16 + quad*4 + rg][wc*32 + nt*16 + l15] = f2bf(fast_tanh(arg[nt][rg]));
        bar_lds();
        #pragma unroll
        for (int ks = 0; ks < 2; ks++){
            bf16x8 paf = *(const bf16x8*)&buf[ps][wr*16 + l15][ks*32 + quad*8];
            #pragma unroll
            for (int dt = 0; dt < 2; dt++)
                hacc[dt] = __builtin_amdgcn_mfma_f32_16x16x32_bf16(paf, pG2[ks][dt], hacc[dt], 0, 0, 0);
        }
        if (jt < 7){
            #pragma unroll
            for (int ks = 0; ks < 2; ks++)
                #pragma unroll
                for (int dt = 0; dt < 2; dt++)
                    pG2[ks][dt] = *(const bf16x8*)&XWtb[((((long)jt+1)*4 + wc*2+dt)*2 + ks)*512 + lane*8];
        }
    }
    #pragma unroll
    for (int dt = 0; dt < 2; dt++){
        float bw = bias_W[wc*32 + dt*16 + l15];
        #pragma unroll
        for (int rg = 0; rg < 4; rg++)
            H[((long)b*NN + i0 + wr*16 + quad*4 + rg)*FD + wc*32 + dt*16 + l15] = hacc[dt][rg] + bw;
    }
}

extern "C" void kernel_launch(void* const* d_in, const int* in_sizes, int n_in,
                              void* d_out, int out_size, void* d_ws, size_t ws_size,
                              hipStream_t stream){
    const float* X      = (const float*)d_in[0];
    const float* A      = (const float*)d_in[1];
    const int*   N      = (const int*)  d_in[2];
    const float* W      = (const float*)d_in[3];
    const float* a      = (const float*)d_in[4];
    const float* bias_W = (const float*)d_in[5];
    const float* bias_a = (const float*)d_in[6];
    float* H = (float*)d_out;
    char* ws = (char*)d_ws;

    unsigned short* XWhf = (unsigned short*)(ws);              // 4 MB (frag-linear)
    unsigned short* XWtf = (unsigned short*)(ws + (4u<<20));   // 4 MB (frag-linear)

    k_xw   <<<BB * NN / 64, 256, 0, stream>>>(X, W, XWhf, XWtf);
    k_fused<<<dim3(BB, 8), 512, 0, stream>>>(A, XWhf, XWtf, a, N, bias_a, bias_W, H);
}